// Round 1
// baseline (1959.237 us; speedup 1.0000x reference)
//
#include <hip/hip_runtime.h>
#include <hip/hip_bf16.h>

#define D_IN 128

// ---------------- degree count ----------------
__global__ __launch_bounds__(256) void deg_kernel(const int* __restrict__ dst,
                                                  float* __restrict__ cnt,
                                                  long long E) {
    long long gid = (long long)blockIdx.x * 256 + threadIdx.x;
    if (gid < E) atomicAdd(&cnt[dst[gid]], 1.0f);
}

__global__ __launch_bounds__(256) void inv_kernel(float* __restrict__ cnt, int N) {
    int i = blockIdx.x * 256 + threadIdx.x;
    if (i < N) cnt[i] = 1.0f / fmaxf(cnt[i], 1.0f);
}

// ---------------- scatter: agg[dst] += w * feat[src] ----------------
__global__ __launch_bounds__(256) void scatter_kernel(const float* __restrict__ feat,
                                                      const int* __restrict__ src,
                                                      const int* __restrict__ dst,
                                                      const float* __restrict__ ew,
                                                      float* __restrict__ agg,
                                                      long long E) {
    long long gid = (long long)blockIdx.x * 256 + threadIdx.x;
    long long e = gid >> 7;           // edge index
    int f = (int)(gid & 127);         // feature index
    if (e >= E) return;
    int s = src[e];
    int d = dst[e];
    float w = ew[e];
    atomicAdd(&agg[(size_t)d * D_IN + f], w * feat[(size_t)s * D_IN + f]);
}

// ---------------- fused GEMM: out = (agg*inv) @ Wrel + b + xin @ Wroot ----------------
// Block: 256 threads. Each block: 128 nodes x 64 output cols.
// LDS: Wrel/Wroot column-tile [128][64] f32 (pad to 68).
template <int DOUT>
__global__ __launch_bounds__(256) void gemm_fused(const float* __restrict__ agg,
                                                  const float* __restrict__ inv_cnt,
                                                  const float* __restrict__ xin,
                                                  const float* __restrict__ Wrel,
                                                  const float* __restrict__ bias,
                                                  const float* __restrict__ Wroot,
                                                  float* __restrict__ out,
                                                  int N) {
    __shared__ float Wr_s[128][68];
    __shared__ float Wo_s[128][68];
    __shared__ float b_s[64];

    const int tid = threadIdx.x;
    const int jbase = blockIdx.y * 64;

    for (int idx = tid; idx < 128 * 64; idx += 256) {
        int k = idx >> 6;
        int j = idx & 63;
        Wr_s[k][j] = Wrel[(size_t)k * DOUT + jbase + j];
        Wo_s[k][j] = Wroot[(size_t)k * DOUT + jbase + j];
    }
    if (tid < 64) b_s[tid] = bias[jbase + tid];
    __syncthreads();

    const int j4 = (tid & 15) * 4;   // col within tile (x4)
    const int r = tid >> 4;          // node lane 0..15
    const int n0 = blockIdx.x * 128;

    for (int it = 0; it < 8; ++it) {
        int n = n0 + it * 16 + r;
        if (n >= N) break;
        float inv = inv_cnt[n];
        const float4* a4 = reinterpret_cast<const float4*>(agg + (size_t)n * D_IN);
        const float4* x4 = reinterpret_cast<const float4*>(xin + (size_t)n * D_IN);
        float acc0 = 0.f, acc1 = 0.f, acc2 = 0.f, acc3 = 0.f;

#pragma unroll 4
        for (int kb = 0; kb < 32; ++kb) {
            float4 am = a4[kb];
            float4 ax = x4[kb];
            const int k = kb * 4;
#define STEP(AM, AX, KK)                                                    \
            {                                                               \
                float a_m = (AM) * inv;                                     \
                float a_x = (AX);                                           \
                float4 wr = *reinterpret_cast<const float4*>(&Wr_s[KK][j4]);\
                float4 wo = *reinterpret_cast<const float4*>(&Wo_s[KK][j4]);\
                acc0 += a_m * wr.x + a_x * wo.x;                            \
                acc1 += a_m * wr.y + a_x * wo.y;                            \
                acc2 += a_m * wr.z + a_x * wo.z;                            \
                acc3 += a_m * wr.w + a_x * wo.w;                            \
            }
            STEP(am.x, ax.x, k + 0)
            STEP(am.y, ax.y, k + 1)
            STEP(am.z, ax.z, k + 2)
            STEP(am.w, ax.w, k + 3)
#undef STEP
        }

        float4 o;
        o.x = acc0 + b_s[j4 + 0];
        o.y = acc1 + b_s[j4 + 1];
        o.z = acc2 + b_s[j4 + 2];
        o.w = acc3 + b_s[j4 + 3];
        *reinterpret_cast<float4*>(&out[(size_t)n * DOUT + jbase + j4]) = o;
    }
}

extern "C" void kernel_launch(void* const* d_in, const int* in_sizes, int n_in,
                              void* d_out, int out_size, void* d_ws, size_t ws_size,
                              hipStream_t stream) {
    const float* x      = (const float*)d_in[0];
    const int*   ei     = (const int*)d_in[1];
    const float* ew     = (const float*)d_in[2];
    const float* Wrel1  = (const float*)d_in[3];
    const float* b1     = (const float*)d_in[4];
    const float* Wroot1 = (const float*)d_in[5];
    const float* Wrel2  = (const float*)d_in[6];
    const float* b2     = (const float*)d_in[7];
    const float* Wroot2 = (const float*)d_in[8];
    float* out = (float*)d_out;

    const int N = in_sizes[0] / D_IN;
    const long long E = in_sizes[2];
    const int* src = ei;
    const int* dst = ei + E;

    // workspace layout: [cnt N | agg N*128 | h N*128]
    float* cnt = (float*)d_ws;
    float* agg = cnt + N;
    float* h   = agg + (size_t)N * D_IN;

    // zero cnt + agg
    hipMemsetAsync(cnt, 0, (size_t)(N + (size_t)N * D_IN) * sizeof(float), stream);

    // degrees -> inverse
    {
        int blocks = (int)((E + 255) / 256);
        deg_kernel<<<blocks, 256, 0, stream>>>(dst, cnt, E);
        inv_kernel<<<(N + 255) / 256, 256, 0, stream>>>(cnt, N);
    }

    // layer 1 scatter
    {
        long long total = E * D_IN;
        int blocks = (int)((total + 255) / 256);
        scatter_kernel<<<blocks, 256, 0, stream>>>(x, src, dst, ew, agg, E);
    }

    // layer 1 gemm -> h
    {
        dim3 grid((N + 127) / 128, 2);
        gemm_fused<128><<<grid, 256, 0, stream>>>(agg, cnt, x, Wrel1, b1, Wroot1, h, N);
    }

    // zero agg, layer 2 scatter
    hipMemsetAsync(agg, 0, (size_t)N * D_IN * sizeof(float), stream);
    {
        long long total = E * D_IN;
        int blocks = (int)((total + 255) / 256);
        scatter_kernel<<<blocks, 256, 0, stream>>>(h, src, dst, ew, agg, E);
    }

    // layer 2 gemm -> out
    {
        dim3 grid((N + 127) / 128, 4);
        gemm_fused<256><<<grid, 256, 0, stream>>>(agg, cnt, h, Wrel2, b2, Wroot2, out, N);
    }
}

// Round 2
// 927.764 us; speedup vs baseline: 2.1118x; 2.1118x over previous
//
#include <hip/hip_runtime.h>
#include <hip/hip_bf16.h>

#define D_IN 128

// ======================= sort-by-dst machinery =======================

__global__ __launch_bounds__(256) void hist_kernel(const int* __restrict__ dst,
                                                   int* __restrict__ hist,
                                                   long long E) {
    long long gid = (long long)blockIdx.x * 256 + threadIdx.x;
    if (gid < E) atomicAdd(&hist[dst[gid]], 1);
}

// pass 1: per-block sums of 1024 hist entries
__global__ __launch_bounds__(256) void scan_block_sums(const int* __restrict__ hist,
                                                       int* __restrict__ partial,
                                                       int N) {
    __shared__ int sdata[256];
    int b = blockIdx.x, t = threadIdx.x;
    int base = b * 1024 + t * 4;
    int s = 0;
#pragma unroll
    for (int i = 0; i < 4; ++i) {
        int idx = base + i;
        if (idx < N) s += hist[idx];
    }
    sdata[t] = s;
    __syncthreads();
    for (int off = 128; off > 0; off >>= 1) {
        if (t < off) sdata[t] += sdata[t + off];
        __syncthreads();
    }
    if (t == 0) partial[b] = sdata[0];
}

// pass 2: serial exclusive scan of block partials (nb ~ 98, trivial)
__global__ void scan_partials(int* __restrict__ partial, int nb) {
    if (threadIdx.x == 0 && blockIdx.x == 0) {
        int run = 0;
        for (int i = 0; i < nb; ++i) {
            int t = partial[i];
            partial[i] = run;
            run += t;
        }
    }
}

// pass 3: final exclusive scan -> off[]
__global__ __launch_bounds__(256) void scan_final(const int* __restrict__ hist,
                                                  const int* __restrict__ partial,
                                                  int* __restrict__ off,
                                                  int N) {
    __shared__ int sdata[256];
    int b = blockIdx.x, t = threadIdx.x;
    int base = b * 1024 + t * 4;
    int v[4];
    int s = 0;
#pragma unroll
    for (int i = 0; i < 4; ++i) {
        int idx = base + i;
        v[i] = (idx < N) ? hist[idx] : 0;
        s += v[i];
    }
    sdata[t] = s;
    __syncthreads();
    // Hillis-Steele inclusive scan of thread sums
    for (int o = 1; o < 256; o <<= 1) {
        int tmp = 0;
        if (t >= o) tmp = sdata[t - o];
        __syncthreads();
        sdata[t] += tmp;
        __syncthreads();
    }
    int run = partial[b] + (sdata[t] - s);  // exclusive prefix for this thread
#pragma unroll
    for (int i = 0; i < 4; ++i) {
        int idx = base + i;
        if (idx < N) off[idx] = run;
        run += v[i];
    }
}

__global__ __launch_bounds__(256) void reorder_kernel(const int* __restrict__ src,
                                                      const int* __restrict__ dst,
                                                      const float* __restrict__ ew,
                                                      const int* __restrict__ off,
                                                      int* __restrict__ fill,
                                                      int* __restrict__ ssrc,
                                                      float* __restrict__ sw,
                                                      long long E) {
    long long gid = (long long)blockIdx.x * 256 + threadIdx.x;
    if (gid >= E) return;
    int d = dst[gid];
    int p = off[d] + atomicAdd(&fill[d], 1);
    ssrc[p] = src[gid];
    sw[p] = ew[gid];
}

// =============== segmented aggregation: agg[n] = mean_e w_e * feat[src_e] ===============
// one wave per node; lane holds 2 features (float2)
__global__ __launch_bounds__(256) void aggregate_kernel(const float* __restrict__ feat,
                                                        const int* __restrict__ ssrc,
                                                        const float* __restrict__ sw,
                                                        const int* __restrict__ off,
                                                        const int* __restrict__ hist,
                                                        float* __restrict__ agg,
                                                        int N) {
    int node = blockIdx.x * 4 + (threadIdx.x >> 6);
    if (node >= N) return;
    int lane = threadIdx.x & 63;
    int start = off[node];
    int cnt = hist[node];
    int end = start + cnt;
    float inv = 1.0f / fmaxf((float)cnt, 1.0f);

    const float2* f2 = reinterpret_cast<const float2*>(feat);
    float ax = 0.f, ay = 0.f;
    int e = start;
    for (; e + 1 < end; e += 2) {
        int s0 = ssrc[e], s1 = ssrc[e + 1];
        float w0 = sw[e], w1 = sw[e + 1];
        float2 v0 = f2[(size_t)s0 * 64 + lane];
        float2 v1 = f2[(size_t)s1 * 64 + lane];
        ax += w0 * v0.x + w1 * v1.x;
        ay += w0 * v0.y + w1 * v1.y;
    }
    if (e < end) {
        int s0 = ssrc[e];
        float w0 = sw[e];
        float2 v0 = f2[(size_t)s0 * 64 + lane];
        ax += w0 * v0.x;
        ay += w0 * v0.y;
    }
    float2 o;
    o.x = ax * inv;
    o.y = ay * inv;
    reinterpret_cast<float2*>(agg)[(size_t)node * 64 + lane] = o;
}

// =============== fused GEMM: out = agg @ Wrel + b + xin @ Wroot ===============
// (agg already holds the mean)
template <int DOUT>
__global__ __launch_bounds__(256) void gemm_fused(const float* __restrict__ agg,
                                                  const float* __restrict__ xin,
                                                  const float* __restrict__ Wrel,
                                                  const float* __restrict__ bias,
                                                  const float* __restrict__ Wroot,
                                                  float* __restrict__ out,
                                                  int N) {
    __shared__ float Wr_s[128][68];
    __shared__ float Wo_s[128][68];
    __shared__ float b_s[64];

    const int tid = threadIdx.x;
    const int jbase = blockIdx.y * 64;

    for (int idx = tid; idx < 128 * 64; idx += 256) {
        int k = idx >> 6;
        int j = idx & 63;
        Wr_s[k][j] = Wrel[(size_t)k * DOUT + jbase + j];
        Wo_s[k][j] = Wroot[(size_t)k * DOUT + jbase + j];
    }
    if (tid < 64) b_s[tid] = bias[jbase + tid];
    __syncthreads();

    const int j4 = (tid & 15) * 4;
    const int r = tid >> 4;
    const int n0 = blockIdx.x * 128;

    for (int it = 0; it < 8; ++it) {
        int n = n0 + it * 16 + r;
        if (n >= N) break;
        const float4* a4 = reinterpret_cast<const float4*>(agg + (size_t)n * D_IN);
        const float4* x4 = reinterpret_cast<const float4*>(xin + (size_t)n * D_IN);
        float acc0 = 0.f, acc1 = 0.f, acc2 = 0.f, acc3 = 0.f;

#pragma unroll 4
        for (int kb = 0; kb < 32; ++kb) {
            float4 am = a4[kb];
            float4 ax = x4[kb];
            const int k = kb * 4;
#define STEP(AM, AX, KK)                                                    \
            {                                                               \
                float a_m = (AM);                                           \
                float a_x = (AX);                                           \
                float4 wr = *reinterpret_cast<const float4*>(&Wr_s[KK][j4]);\
                float4 wo = *reinterpret_cast<const float4*>(&Wo_s[KK][j4]);\
                acc0 += a_m * wr.x + a_x * wo.x;                            \
                acc1 += a_m * wr.y + a_x * wo.y;                            \
                acc2 += a_m * wr.z + a_x * wo.z;                            \
                acc3 += a_m * wr.w + a_x * wo.w;                            \
            }
            STEP(am.x, ax.x, k + 0)
            STEP(am.y, ax.y, k + 1)
            STEP(am.z, ax.z, k + 2)
            STEP(am.w, ax.w, k + 3)
#undef STEP
        }

        float4 o;
        o.x = acc0 + b_s[j4 + 0];
        o.y = acc1 + b_s[j4 + 1];
        o.z = acc2 + b_s[j4 + 2];
        o.w = acc3 + b_s[j4 + 3];
        *reinterpret_cast<float4*>(&out[(size_t)n * DOUT + jbase + j4]) = o;
    }
}

// ======================= fallback (atomic scatter) =======================

__global__ __launch_bounds__(256) void inv_from_hist(const int* __restrict__ hist,
                                                     float* __restrict__ inv, int N) {
    int i = blockIdx.x * 256 + threadIdx.x;
    if (i < N) inv[i] = 1.0f / fmaxf((float)hist[i], 1.0f);
}

__global__ __launch_bounds__(256) void scatter_kernel(const float* __restrict__ feat,
                                                      const int* __restrict__ src,
                                                      const int* __restrict__ dst,
                                                      const float* __restrict__ ew,
                                                      float* __restrict__ agg,
                                                      long long E) {
    long long gid = (long long)blockIdx.x * 256 + threadIdx.x;
    long long e = gid >> 7;
    int f = (int)(gid & 127);
    if (e >= E) return;
    int s = src[e];
    int d = dst[e];
    float w = ew[e];
    atomicAdd(&agg[(size_t)d * D_IN + f], w * feat[(size_t)s * D_IN + f]);
}

__global__ __launch_bounds__(256) void scale_mean(float* __restrict__ agg,
                                                  const float* __restrict__ inv, int N) {
    int gid = blockIdx.x * 256 + threadIdx.x;
    int n = gid >> 6;
    int l = gid & 63;
    if (n >= N) return;
    float iv = inv[n];
    float2 v = reinterpret_cast<float2*>(agg)[(size_t)n * 64 + l];
    v.x *= iv; v.y *= iv;
    reinterpret_cast<float2*>(agg)[(size_t)n * 64 + l] = v;
}

// ======================= launch =======================

extern "C" void kernel_launch(void* const* d_in, const int* in_sizes, int n_in,
                              void* d_out, int out_size, void* d_ws, size_t ws_size,
                              hipStream_t stream) {
    const float* x      = (const float*)d_in[0];
    const int*   ei     = (const int*)d_in[1];
    const float* ew     = (const float*)d_in[2];
    const float* Wrel1  = (const float*)d_in[3];
    const float* b1     = (const float*)d_in[4];
    const float* Wroot1 = (const float*)d_in[5];
    const float* Wrel2  = (const float*)d_in[6];
    const float* b2     = (const float*)d_in[7];
    const float* Wroot2 = (const float*)d_in[8];
    float* out = (float*)d_out;

    const int N = in_sizes[0] / D_IN;
    const long long E = in_sizes[2];
    const int* src = ei;
    const int* dst = ei + E;

    const int eb = (int)((E + 255) / 256);
    const int nb1024 = (N + 1023) / 1024;

    // workspace layout (all 4-byte elems):
    // [hist N][fill N][off N][partial nb1024(pad 128)][ssrc E][sw E][agg N*128][h N*128]
    size_t need = ((size_t)3 * N + 128 + 2 * (size_t)E + 2 * (size_t)N * D_IN) * 4;

    if (ws_size >= need) {
        int* hist   = (int*)d_ws;
        int* fill   = hist + N;
        int* off    = fill + N;
        int* part   = off + N;
        int* ssrc   = part + 128;
        float* sw   = (float*)(ssrc + E);
        float* agg  = sw + E;
        float* h    = agg + (size_t)N * D_IN;

        hipMemsetAsync(hist, 0, (size_t)2 * N * sizeof(int), stream);  // hist + fill

        hist_kernel<<<eb, 256, 0, stream>>>(dst, hist, E);
        scan_block_sums<<<nb1024, 256, 0, stream>>>(hist, part, N);
        scan_partials<<<1, 64, 0, stream>>>(part, nb1024);
        scan_final<<<nb1024, 256, 0, stream>>>(hist, part, off, N);
        reorder_kernel<<<eb, 256, 0, stream>>>(src, dst, ew, off, fill, ssrc, sw, E);

        const int ab = (N + 3) / 4;
        // layer 1
        aggregate_kernel<<<ab, 256, 0, stream>>>(x, ssrc, sw, off, hist, agg, N);
        {
            dim3 grid((N + 127) / 128, 2);
            gemm_fused<128><<<grid, 256, 0, stream>>>(agg, x, Wrel1, b1, Wroot1, h, N);
        }
        // layer 2
        aggregate_kernel<<<ab, 256, 0, stream>>>(h, ssrc, sw, off, hist, agg, N);
        {
            dim3 grid((N + 127) / 128, 4);
            gemm_fused<256><<<grid, 256, 0, stream>>>(agg, h, Wrel2, b2, Wroot2, out, N);
        }
    } else {
        // fallback: atomic scatter path (round-1 behavior)
        int* hist  = (int*)d_ws;
        float* inv = (float*)(hist + N);
        float* agg = inv + N;
        float* h   = agg + (size_t)N * D_IN;

        hipMemsetAsync(hist, 0, (size_t)N * sizeof(int), stream);
        hipMemsetAsync(agg, 0, (size_t)N * D_IN * sizeof(float), stream);

        hist_kernel<<<eb, 256, 0, stream>>>(dst, hist, E);
        inv_from_hist<<<(N + 255) / 256, 256, 0, stream>>>(hist, inv, N);

        long long total = E * D_IN;
        int fb = (int)((total + 255) / 256);
        scatter_kernel<<<fb, 256, 0, stream>>>(x, src, dst, ew, agg, E);
        scale_mean<<<(N * 64 + 255) / 256, 256, 0, stream>>>(agg, inv, N);
        {
            dim3 grid((N + 127) / 128, 2);
            gemm_fused<128><<<grid, 256, 0, stream>>>(agg, x, Wrel1, b1, Wroot1, h, N);
        }
        hipMemsetAsync(agg, 0, (size_t)N * D_IN * sizeof(float), stream);
        scatter_kernel<<<fb, 256, 0, stream>>>(h, src, dst, ew, agg, E);
        scale_mean<<<(N * 64 + 255) / 256, 256, 0, stream>>>(agg, inv, N);
        {
            dim3 grid((N + 127) / 128, 4);
            gemm_fused<256><<<grid, 256, 0, stream>>>(agg, h, Wrel2, b2, Wroot2, out, N);
        }
    }
}

// Round 3
// 512.479 us; speedup vs baseline: 3.8231x; 1.8103x over previous
//
#include <hip/hip_runtime.h>
#include <hip/hip_bf16.h>

#define D_IN 128

typedef __attribute__((ext_vector_type(8))) short bf16x8;
typedef __attribute__((ext_vector_type(4))) float f32x4;

// ======================= sort-by-dst machinery =======================

__global__ __launch_bounds__(256) void hist_kernel(const int* __restrict__ dst,
                                                   int* __restrict__ hist,
                                                   long long E) {
    long long gid = (long long)blockIdx.x * 256 + threadIdx.x;
    if (gid < E) atomicAdd(&hist[dst[gid]], 1);
}

__global__ __launch_bounds__(256) void scan_block_sums(const int* __restrict__ hist,
                                                       int* __restrict__ partial,
                                                       int N) {
    __shared__ int sdata[256];
    int b = blockIdx.x, t = threadIdx.x;
    int base = b * 1024 + t * 4;
    int s = 0;
#pragma unroll
    for (int i = 0; i < 4; ++i) {
        int idx = base + i;
        if (idx < N) s += hist[idx];
    }
    sdata[t] = s;
    __syncthreads();
    for (int off = 128; off > 0; off >>= 1) {
        if (t < off) sdata[t] += sdata[t + off];
        __syncthreads();
    }
    if (t == 0) partial[b] = sdata[0];
}

__global__ void scan_partials(int* __restrict__ partial, int nb) {
    if (threadIdx.x == 0 && blockIdx.x == 0) {
        int run = 0;
        for (int i = 0; i < nb; ++i) {
            int t = partial[i];
            partial[i] = run;
            run += t;
        }
    }
}

__global__ __launch_bounds__(256) void scan_final(const int* __restrict__ hist,
                                                  const int* __restrict__ partial,
                                                  int* __restrict__ off,
                                                  int N) {
    __shared__ int sdata[256];
    int b = blockIdx.x, t = threadIdx.x;
    int base = b * 1024 + t * 4;
    int v[4];
    int s = 0;
#pragma unroll
    for (int i = 0; i < 4; ++i) {
        int idx = base + i;
        v[i] = (idx < N) ? hist[idx] : 0;
        s += v[i];
    }
    sdata[t] = s;
    __syncthreads();
    for (int o = 1; o < 256; o <<= 1) {
        int tmp = 0;
        if (t >= o) tmp = sdata[t - o];
        __syncthreads();
        sdata[t] += tmp;
        __syncthreads();
    }
    int run = partial[b] + (sdata[t] - s);
#pragma unroll
    for (int i = 0; i < 4; ++i) {
        int idx = base + i;
        if (idx < N) off[idx] = run;
        run += v[i];
    }
}

// consumes off[] destructively (re-scan afterwards)
__global__ __launch_bounds__(256) void reorder_kernel(const int* __restrict__ src,
                                                      const int* __restrict__ dst,
                                                      const float* __restrict__ ew,
                                                      int* __restrict__ off,
                                                      int* __restrict__ ssrc,
                                                      float* __restrict__ sw,
                                                      long long E) {
    long long gid = (long long)blockIdx.x * 256 + threadIdx.x;
    if (gid >= E) return;
    int d = dst[gid];
    int p = atomicAdd(&off[d], 1);
    ssrc[p] = src[gid];
    sw[p] = ew[gid];
}

// ======================= dtype conversions =======================

__global__ __launch_bounds__(256) void conv_x_kernel(const float* __restrict__ x,
                                                     __hip_bfloat16* __restrict__ xb,
                                                     long long total4) {
    long long i = (long long)blockIdx.x * 256 + threadIdx.x;
    if (i >= total4) return;
    float4 v = reinterpret_cast<const float4*>(x)[i];
    union { ushort4 u; __hip_bfloat162 h2[2]; } o;
    o.h2[0] = __float22bfloat162_rn(make_float2(v.x, v.y));
    o.h2[1] = __float22bfloat162_rn(make_float2(v.z, v.w));
    reinterpret_cast<ushort4*>(xb)[i] = o.u;
}

// Wt[j][k] = (k<128 ? Wrel[k][j] : Wroot[k-128][j]), bf16
template <int DOUT>
__global__ __launch_bounds__(256) void conv_w_kernel(const float* __restrict__ Wrel,
                                                     const float* __restrict__ Wroot,
                                                     __hip_bfloat16* __restrict__ Wt) {
    int idx = blockIdx.x * 256 + threadIdx.x;
    if (idx >= DOUT * 256) return;
    int j = idx >> 8;
    int k = idx & 255;
    float v = (k < 128) ? Wrel[(size_t)k * DOUT + j] : Wroot[(size_t)(k - 128) * DOUT + j];
    Wt[idx] = __float2bfloat16(v);
}

// =============== segmented aggregation (bf16 in/out, f32 accum) ===============
__global__ __launch_bounds__(256) void aggregate_kernel(const __hip_bfloat16* __restrict__ featb,
                                                        const int* __restrict__ ssrc,
                                                        const float* __restrict__ sw,
                                                        const int* __restrict__ off,
                                                        const int* __restrict__ hist,
                                                        __hip_bfloat16* __restrict__ aggb,
                                                        int N) {
    int node = blockIdx.x * 4 + (threadIdx.x >> 6);
    if (node >= N) return;
    int lane = threadIdx.x & 63;
    int start = off[node];
    int cnt = hist[node];
    int end = start + cnt;
    float inv = 1.0f / fmaxf((float)cnt, 1.0f);

    const __hip_bfloat162* f2 = reinterpret_cast<const __hip_bfloat162*>(featb);
    float ax = 0.f, ay = 0.f;
    int e = start;
    for (; e + 3 < end; e += 4) {
        int s0 = ssrc[e], s1 = ssrc[e + 1], s2 = ssrc[e + 2], s3 = ssrc[e + 3];
        float w0 = sw[e], w1 = sw[e + 1], w2 = sw[e + 2], w3 = sw[e + 3];
        float2 v0 = __bfloat1622float2(f2[(size_t)s0 * 64 + lane]);
        float2 v1 = __bfloat1622float2(f2[(size_t)s1 * 64 + lane]);
        float2 v2 = __bfloat1622float2(f2[(size_t)s2 * 64 + lane]);
        float2 v3 = __bfloat1622float2(f2[(size_t)s3 * 64 + lane]);
        ax += w0 * v0.x + w1 * v1.x + w2 * v2.x + w3 * v3.x;
        ay += w0 * v0.y + w1 * v1.y + w2 * v2.y + w3 * v3.y;
    }
    for (; e < end; ++e) {
        int s0 = ssrc[e];
        float w0 = sw[e];
        float2 v0 = __bfloat1622float2(f2[(size_t)s0 * 64 + lane]);
        ax += w0 * v0.x;
        ay += w0 * v0.y;
    }
    reinterpret_cast<__hip_bfloat162*>(aggb)[(size_t)node * 64 + lane] =
        __float22bfloat162_rn(make_float2(ax * inv, ay * inv));
}

// =============== MFMA GEMM: out = [Arel|Aroot] @ Wt^T + bias ===============
// Arel/Aroot: [M][128] bf16 row-major. Wt: [DOUT][256] bf16 (row j = K-concat).
// Block 256 thr = 4 waves (2x2), block tile 64x64, wave tile 32x32.
template <int DOUT, bool OUT_BF16>
__global__ __launch_bounds__(256) void gemm_mfma(const __hip_bfloat16* __restrict__ Arel,
                                                 const __hip_bfloat16* __restrict__ Aroot,
                                                 const __hip_bfloat16* __restrict__ Wt,
                                                 const float* __restrict__ bias,
                                                 void* __restrict__ outp,
                                                 int M) {
    const int tid = threadIdx.x;
    const int lane = tid & 63;
    const int wave = tid >> 6;
    const int lr = lane & 15;       // A-row / B-col / D-col within 16-tile
    const int lk = lane >> 4;       // k-group 0..3
    const int mbase = blockIdx.x * 64 + (wave >> 1) * 32;
    const int nbase = blockIdx.y * 64 + (wave & 1) * 32;

    // B fragments: 2 n-tiles x 8 k-steps (full K=256), resident in regs
    bf16x8 bfrag[2][8];
#pragma unroll
    for (int ni = 0; ni < 2; ++ni) {
        const short* wrow = (const short*)Wt + (size_t)(nbase + ni * 16 + lr) * 256 + lk * 8;
#pragma unroll
        for (int kk = 0; kk < 8; ++kk)
            bfrag[ni][kk] = *reinterpret_cast<const bf16x8*>(wrow + kk * 32);
    }

    f32x4 zero = {0.f, 0.f, 0.f, 0.f};
    f32x4 acc[2][2] = {{zero, zero}, {zero, zero}};

#pragma unroll
    for (int mi = 0; mi < 2; ++mi) {
        int row = mbase + mi * 16 + lr;
        int rc = row < M ? row : M - 1;   // clamp; store is guarded
        const short* ar = (const short*)Arel  + (size_t)rc * 128 + lk * 8;
        const short* ax = (const short*)Aroot + (size_t)rc * 128 + lk * 8;
#pragma unroll
        for (int kk = 0; kk < 4; ++kk) {
            bf16x8 af = *reinterpret_cast<const bf16x8*>(ar + kk * 32);
            acc[mi][0] = __builtin_amdgcn_mfma_f32_16x16x32_bf16(af, bfrag[0][kk], acc[mi][0], 0, 0, 0);
            acc[mi][1] = __builtin_amdgcn_mfma_f32_16x16x32_bf16(af, bfrag[1][kk], acc[mi][1], 0, 0, 0);
        }
#pragma unroll
        for (int kk = 0; kk < 4; ++kk) {
            bf16x8 af = *reinterpret_cast<const bf16x8*>(ax + kk * 32);
            acc[mi][0] = __builtin_amdgcn_mfma_f32_16x16x32_bf16(af, bfrag[0][kk + 4], acc[mi][0], 0, 0, 0);
            acc[mi][1] = __builtin_amdgcn_mfma_f32_16x16x32_bf16(af, bfrag[1][kk + 4], acc[mi][1], 0, 0, 0);
        }
    }

    // epilogue: D[row][col], col = lr, row = lk*4 + r
#pragma unroll
    for (int mi = 0; mi < 2; ++mi)
#pragma unroll
        for (int ni = 0; ni < 2; ++ni) {
            int col = nbase + ni * 16 + lr;
            float bv = bias[col];
#pragma unroll
            for (int r = 0; r < 4; ++r) {
                int row = mbase + mi * 16 + lk * 4 + r;
                if (row < M) {
                    float v = acc[mi][ni][r] + bv;
                    if (OUT_BF16)
                        ((__hip_bfloat16*)outp)[(size_t)row * DOUT + col] = __float2bfloat16(v);
                    else
                        ((float*)outp)[(size_t)row * DOUT + col] = v;
                }
            }
        }
}

// ======================= launch =======================

extern "C" void kernel_launch(void* const* d_in, const int* in_sizes, int n_in,
                              void* d_out, int out_size, void* d_ws, size_t ws_size,
                              hipStream_t stream) {
    const float* x      = (const float*)d_in[0];
    const int*   ei     = (const int*)d_in[1];
    const float* ew     = (const float*)d_in[2];
    const float* Wrel1  = (const float*)d_in[3];
    const float* b1     = (const float*)d_in[4];
    const float* Wroot1 = (const float*)d_in[5];
    const float* Wrel2  = (const float*)d_in[6];
    const float* b2     = (const float*)d_in[7];
    const float* Wroot2 = (const float*)d_in[8];
    float* out = (float*)d_out;

    const int N = in_sizes[0] / D_IN;
    const long long E = in_sizes[2];
    const int* src = ei;
    const int* dst = ei + E;

    const int eb = (int)((E + 255) / 256);
    const int nb1024 = (N + 1023) / 1024;

    // workspace layout (bytes):
    // [hist N i32][off N i32][part 128 i32][ssrc E i32][sw E f32]
    // [agg1b M*128 bf16][xb M*128 bf16][agg2b M*128 bf16][hb M*128 bf16]
    // [Wt1 128*256 bf16][Wt2 256*256 bf16]
    int* hist = (int*)d_ws;
    int* off  = hist + N;
    int* part = off + N;
    int* ssrc = part + 128;
    float* sw = (float*)(ssrc + E);
    __hip_bfloat16* agg1b = (__hip_bfloat16*)(sw + E);
    __hip_bfloat16* xb    = agg1b + (size_t)N * D_IN;
    __hip_bfloat16* agg2b = xb    + (size_t)N * D_IN;
    __hip_bfloat16* hb    = agg2b + (size_t)N * D_IN;
    __hip_bfloat16* Wt1   = hb    + (size_t)N * D_IN;
    __hip_bfloat16* Wt2   = Wt1   + 128 * 256;

    // ---- sort edges by dst (histogram -> scan -> reorder -> re-scan) ----
    hipMemsetAsync(hist, 0, (size_t)N * sizeof(int), stream);
    hist_kernel<<<eb, 256, 0, stream>>>(dst, hist, E);
    scan_block_sums<<<nb1024, 256, 0, stream>>>(hist, part, N);
    scan_partials<<<1, 64, 0, stream>>>(part, nb1024);
    scan_final<<<nb1024, 256, 0, stream>>>(hist, part, off, N);
    reorder_kernel<<<eb, 256, 0, stream>>>(src, dst, ew, off, ssrc, sw, E);
    scan_block_sums<<<nb1024, 256, 0, stream>>>(hist, part, N);
    scan_partials<<<1, 64, 0, stream>>>(part, nb1024);
    scan_final<<<nb1024, 256, 0, stream>>>(hist, part, off, N);

    // ---- conversions ----
    {
        long long total4 = (long long)N * D_IN / 4;
        conv_x_kernel<<<(int)((total4 + 255) / 256), 256, 0, stream>>>(x, xb, total4);
        conv_w_kernel<128><<<(128 * 256 + 255) / 256, 256, 0, stream>>>(Wrel1, Wroot1, Wt1);
        conv_w_kernel<256><<<(256 * 256 + 255) / 256, 256, 0, stream>>>(Wrel2, Wroot2, Wt2);
    }

    const int ab = (N + 3) / 4;
    const int gx = (N + 63) / 64;

    // ---- layer 1 ----
    aggregate_kernel<<<ab, 256, 0, stream>>>(xb, ssrc, sw, off, hist, agg1b, N);
    {
        dim3 grid(gx, 2);
        gemm_mfma<128, true><<<grid, 256, 0, stream>>>(agg1b, xb, Wt1, b1, hb, N);
    }

    // ---- layer 2 ----
    aggregate_kernel<<<ab, 256, 0, stream>>>(hb, ssrc, sw, off, hist, agg2b, N);
    {
        dim3 grid(gx, 4);
        gemm_mfma<256, false><<<grid, 256, 0, stream>>>(agg2b, hb, Wt2, b2, out, N);
    }
}

// Round 4
// 479.248 us; speedup vs baseline: 4.0882x; 1.0693x over previous
//
#include <hip/hip_runtime.h>
#include <hip/hip_bf16.h>

#define D_IN 128

typedef __attribute__((ext_vector_type(8))) short bf16x8;
typedef __attribute__((ext_vector_type(4))) float f32x4;

// ======================= sort-by-dst machinery =======================

__global__ __launch_bounds__(256) void hist_kernel(const int* __restrict__ dst,
                                                   int* __restrict__ hist,
                                                   long long E) {
    long long gid = (long long)blockIdx.x * 256 + threadIdx.x;
    if (gid < E) atomicAdd(&hist[dst[gid]], 1);
}

__global__ __launch_bounds__(256) void scan_block_sums(const int* __restrict__ hist,
                                                       int* __restrict__ partial,
                                                       int N) {
    __shared__ int sdata[256];
    int b = blockIdx.x, t = threadIdx.x;
    int base = b * 1024 + t * 4;
    int s = 0;
#pragma unroll
    for (int i = 0; i < 4; ++i) {
        int idx = base + i;
        if (idx < N) s += hist[idx];
    }
    sdata[t] = s;
    __syncthreads();
    for (int off = 128; off > 0; off >>= 1) {
        if (t < off) sdata[t] += sdata[t + off];
        __syncthreads();
    }
    if (t == 0) partial[b] = sdata[0];
}

__global__ void scan_partials(int* __restrict__ partial, int nb) {
    if (threadIdx.x == 0 && blockIdx.x == 0) {
        int run = 0;
        for (int i = 0; i < nb; ++i) {
            int t = partial[i];
            partial[i] = run;
            run += t;
        }
    }
}

__global__ __launch_bounds__(256) void scan_final(const int* __restrict__ hist,
                                                  const int* __restrict__ partial,
                                                  int* __restrict__ off,
                                                  int N) {
    __shared__ int sdata[256];
    int b = blockIdx.x, t = threadIdx.x;
    int base = b * 1024 + t * 4;
    int v[4];
    int s = 0;
#pragma unroll
    for (int i = 0; i < 4; ++i) {
        int idx = base + i;
        v[i] = (idx < N) ? hist[idx] : 0;
        s += v[i];
    }
    sdata[t] = s;
    __syncthreads();
    for (int o = 1; o < 256; o <<= 1) {
        int tmp = 0;
        if (t >= o) tmp = sdata[t - o];
        __syncthreads();
        sdata[t] += tmp;
        __syncthreads();
    }
    int run = partial[b] + (sdata[t] - s);
#pragma unroll
    for (int i = 0; i < 4; ++i) {
        int idx = base + i;
        if (idx < N) off[idx] = run;
        run += v[i];
    }
}

// consumes off[] destructively; afterwards off[d] = inclusive prefix (seg end)
__global__ __launch_bounds__(256) void reorder_kernel(const int* __restrict__ src,
                                                      const int* __restrict__ dst,
                                                      const float* __restrict__ ew,
                                                      int* __restrict__ off,
                                                      int2* __restrict__ edges,
                                                      long long E) {
    long long gid = (long long)blockIdx.x * 256 + threadIdx.x;
    if (gid >= E) return;
    int d = dst[gid];
    int p = atomicAdd(&off[d], 1);
    edges[p] = make_int2(src[gid], __float_as_int(ew[gid]));
}

// ======================= dtype conversions =======================

__global__ __launch_bounds__(256) void conv_x_kernel(const float* __restrict__ x,
                                                     __hip_bfloat16* __restrict__ xb,
                                                     long long total4) {
    long long i = (long long)blockIdx.x * 256 + threadIdx.x;
    if (i >= total4) return;
    float4 v = reinterpret_cast<const float4*>(x)[i];
    union { ushort4 u; __hip_bfloat162 h2[2]; } o;
    o.h2[0] = __float22bfloat162_rn(make_float2(v.x, v.y));
    o.h2[1] = __float22bfloat162_rn(make_float2(v.z, v.w));
    reinterpret_cast<ushort4*>(xb)[i] = o.u;
}

// Wt[j][k] = (k<128 ? Wrel[k][j] : Wroot[k-128][j]), bf16
template <int DOUT>
__global__ __launch_bounds__(256) void conv_w_kernel(const float* __restrict__ Wrel,
                                                     const float* __restrict__ Wroot,
                                                     __hip_bfloat16* __restrict__ Wt) {
    int idx = blockIdx.x * 256 + threadIdx.x;
    if (idx >= DOUT * 256) return;
    int j = idx >> 8;
    int k = idx & 255;
    float v = (k < 128) ? Wrel[(size_t)k * DOUT + j] : Wroot[(size_t)(k - 128) * DOUT + j];
    Wt[idx] = __float2bfloat16(v);
}

// =============== segmented aggregation (bf16 in/out, f32 accum) ===============
// one wave per node; lane holds 2 features (__hip_bfloat162)
__global__ __launch_bounds__(256) void aggregate_kernel(const __hip_bfloat16* __restrict__ featb,
                                                        const int2* __restrict__ edges,
                                                        const int* __restrict__ off,
                                                        const int* __restrict__ hist,
                                                        __hip_bfloat16* __restrict__ aggb,
                                                        int N) {
    int node = blockIdx.x * 4 + (threadIdx.x >> 6);
    if (node >= N) return;
    int lane = threadIdx.x & 63;
    int cnt = hist[node];
    int end = off[node];          // inclusive prefix = segment end
    int start = end - cnt;
    float inv = 1.0f / fmaxf((float)cnt, 1.0f);

    const __hip_bfloat162* f2 = reinterpret_cast<const __hip_bfloat162*>(featb);
    float ax = 0.f, ay = 0.f;
    int e = start;
    for (; e + 7 < end; e += 8) {
        int2 ed[8];
#pragma unroll
        for (int i = 0; i < 8; ++i) ed[i] = edges[e + i];
#pragma unroll
        for (int i = 0; i < 8; ++i) {
            float w = __int_as_float(ed[i].y);
            float2 v = __bfloat1622float2(f2[(size_t)ed[i].x * 64 + lane]);
            ax += w * v.x;
            ay += w * v.y;
        }
    }
    for (; e + 3 < end; e += 4) {
        int2 ed[4];
#pragma unroll
        for (int i = 0; i < 4; ++i) ed[i] = edges[e + i];
#pragma unroll
        for (int i = 0; i < 4; ++i) {
            float w = __int_as_float(ed[i].y);
            float2 v = __bfloat1622float2(f2[(size_t)ed[i].x * 64 + lane]);
            ax += w * v.x;
            ay += w * v.y;
        }
    }
    for (; e < end; ++e) {
        int2 ed = edges[e];
        float w = __int_as_float(ed.y);
        float2 v = __bfloat1622float2(f2[(size_t)ed.x * 64 + lane]);
        ax += w * v.x;
        ay += w * v.y;
    }
    reinterpret_cast<__hip_bfloat162*>(aggb)[(size_t)node * 64 + lane] =
        __float22bfloat162_rn(make_float2(ax * inv, ay * inv));
}

// =============== MFMA GEMM: out = [Arel|Aroot] @ Wt^T + bias ===============
// Arel/Aroot: [M][128] bf16 row-major. Wt: [DOUT][256] bf16 (row j = K-concat).
// Block 256 thr = 4 waves (2x2), block tile 64x64, wave tile 32x32.
template <int DOUT, bool OUT_BF16>
__global__ __launch_bounds__(256) void gemm_mfma(const __hip_bfloat16* __restrict__ Arel,
                                                 const __hip_bfloat16* __restrict__ Aroot,
                                                 const __hip_bfloat16* __restrict__ Wt,
                                                 const float* __restrict__ bias,
                                                 void* __restrict__ outp,
                                                 int M) {
    const int tid = threadIdx.x;
    const int lane = tid & 63;
    const int wave = tid >> 6;
    const int lr = lane & 15;       // A-row / B-col / D-col within 16-tile
    const int lk = lane >> 4;       // k-group 0..3
    const int mbase = blockIdx.x * 64 + (wave >> 1) * 32;
    const int nbase = blockIdx.y * 64 + (wave & 1) * 32;

    // B fragments: 2 n-tiles x 8 k-steps (full K=256), resident in regs
    bf16x8 bfrag[2][8];
#pragma unroll
    for (int ni = 0; ni < 2; ++ni) {
        const short* wrow = (const short*)Wt + (size_t)(nbase + ni * 16 + lr) * 256 + lk * 8;
#pragma unroll
        for (int kk = 0; kk < 8; ++kk)
            bfrag[ni][kk] = *reinterpret_cast<const bf16x8*>(wrow + kk * 32);
    }

    f32x4 zero = {0.f, 0.f, 0.f, 0.f};
    f32x4 acc[2][2] = {{zero, zero}, {zero, zero}};

#pragma unroll
    for (int mi = 0; mi < 2; ++mi) {
        int row = mbase + mi * 16 + lr;
        int rc = row < M ? row : M - 1;   // clamp; store is guarded
        const short* ar = (const short*)Arel  + (size_t)rc * 128 + lk * 8;
        const short* ax = (const short*)Aroot + (size_t)rc * 128 + lk * 8;
#pragma unroll
        for (int kk = 0; kk < 4; ++kk) {
            bf16x8 af = *reinterpret_cast<const bf16x8*>(ar + kk * 32);
            acc[mi][0] = __builtin_amdgcn_mfma_f32_16x16x32_bf16(af, bfrag[0][kk], acc[mi][0], 0, 0, 0);
            acc[mi][1] = __builtin_amdgcn_mfma_f32_16x16x32_bf16(af, bfrag[1][kk], acc[mi][1], 0, 0, 0);
        }
#pragma unroll
        for (int kk = 0; kk < 4; ++kk) {
            bf16x8 af = *reinterpret_cast<const bf16x8*>(ax + kk * 32);
            acc[mi][0] = __builtin_amdgcn_mfma_f32_16x16x32_bf16(af, bfrag[0][kk + 4], acc[mi][0], 0, 0, 0);
            acc[mi][1] = __builtin_amdgcn_mfma_f32_16x16x32_bf16(af, bfrag[1][kk + 4], acc[mi][1], 0, 0, 0);
        }
    }

    // epilogue: D[row][col], col = lr, row = lk*4 + r
#pragma unroll
    for (int mi = 0; mi < 2; ++mi)
#pragma unroll
        for (int ni = 0; ni < 2; ++ni) {
            int col = nbase + ni * 16 + lr;
            float bv = bias[col];
#pragma unroll
            for (int r = 0; r < 4; ++r) {
                int row = mbase + mi * 16 + lk * 4 + r;
                if (row < M) {
                    float v = acc[mi][ni][r] + bv;
                    if (OUT_BF16)
                        ((__hip_bfloat16*)outp)[(size_t)row * DOUT + col] = __float2bfloat16(v);
                    else
                        ((float*)outp)[(size_t)row * DOUT + col] = v;
                }
            }
        }
}

// ======================= launch =======================

extern "C" void kernel_launch(void* const* d_in, const int* in_sizes, int n_in,
                              void* d_out, int out_size, void* d_ws, size_t ws_size,
                              hipStream_t stream) {
    const float* x      = (const float*)d_in[0];
    const int*   ei     = (const int*)d_in[1];
    const float* ew     = (const float*)d_in[2];
    const float* Wrel1  = (const float*)d_in[3];
    const float* b1     = (const float*)d_in[4];
    const float* Wroot1 = (const float*)d_in[5];
    const float* Wrel2  = (const float*)d_in[6];
    const float* b2     = (const float*)d_in[7];
    const float* Wroot2 = (const float*)d_in[8];
    float* out = (float*)d_out;

    const int N = in_sizes[0] / D_IN;
    const long long E = in_sizes[2];
    const int* src = ei;
    const int* dst = ei + E;

    const int eb = (int)((E + 255) / 256);
    const int nb1024 = (N + 1023) / 1024;

    // workspace layout:
    // [hist N i32][off N i32][part 128 i32][edges E int2]
    // [agg1b M*128 bf16][xb M*128 bf16][agg2b M*128 bf16][hb M*128 bf16]
    // [Wt1 128*256 bf16][Wt2 256*256 bf16]
    int* hist = (int*)d_ws;
    int* off  = hist + N;
    int* part = off + N;
    int2* edges = (int2*)(part + 128);
    __hip_bfloat16* agg1b = (__hip_bfloat16*)(edges + E);
    __hip_bfloat16* xb    = agg1b + (size_t)N * D_IN;
    __hip_bfloat16* agg2b = xb    + (size_t)N * D_IN;
    __hip_bfloat16* hb    = agg2b + (size_t)N * D_IN;
    __hip_bfloat16* Wt1   = hb    + (size_t)N * D_IN;
    __hip_bfloat16* Wt2   = Wt1   + 128 * 256;

    // ---- sort edges by dst (histogram -> scan -> reorder) ----
    hipMemsetAsync(hist, 0, (size_t)N * sizeof(int), stream);
    hist_kernel<<<eb, 256, 0, stream>>>(dst, hist, E);
    scan_block_sums<<<nb1024, 256, 0, stream>>>(hist, part, N);
    scan_partials<<<1, 64, 0, stream>>>(part, nb1024);
    scan_final<<<nb1024, 256, 0, stream>>>(hist, part, off, N);
    reorder_kernel<<<eb, 256, 0, stream>>>(src, dst, ew, off, edges, E);
    // off[d] now = inclusive prefix (segment end); no re-scan needed

    // ---- conversions ----
    {
        long long total4 = (long long)N * D_IN / 4;
        conv_x_kernel<<<(int)((total4 + 255) / 256), 256, 0, stream>>>(x, xb, total4);
        conv_w_kernel<128><<<(128 * 256 + 255) / 256, 256, 0, stream>>>(Wrel1, Wroot1, Wt1);
        conv_w_kernel<256><<<(256 * 256 + 255) / 256, 256, 0, stream>>>(Wrel2, Wroot2, Wt2);
    }

    const int ab = (N + 3) / 4;
    const int gx = (N + 63) / 64;

    // ---- layer 1 ----
    aggregate_kernel<<<ab, 256, 0, stream>>>(xb, edges, off, hist, agg1b, N);
    {
        dim3 grid(gx, 2);
        gemm_mfma<128, true><<<grid, 256, 0, stream>>>(agg1b, xb, Wt1, b1, hb, N);
    }

    // ---- layer 2 ----
    aggregate_kernel<<<ab, 256, 0, stream>>>(hb, edges, off, hist, agg2b, N);
    {
        dim3 grid(gx, 4);
        gemm_mfma<256, false><<<grid, 256, 0, stream>>>(agg2b, hb, Wt2, b2, out, N);
    }
}

// Round 5
// 399.038 us; speedup vs baseline: 4.9099x; 1.2010x over previous
//
#include <hip/hip_runtime.h>
#include <hip/hip_bf16.h>

#define D_IN 128
#define SORT_CHUNK 4096
#define NBUCK 256

typedef __attribute__((ext_vector_type(8))) short bf16x8;
typedef __attribute__((ext_vector_type(4))) float f32x4;

// ======================= generic exclusive scan (1024/block) =======================

__global__ __launch_bounds__(256) void scan_block_sums(const int* __restrict__ in,
                                                       int* __restrict__ partial,
                                                       int M) {
    __shared__ int sdata[256];
    int b = blockIdx.x, t = threadIdx.x;
    int base = b * 1024 + t * 4;
    int s = 0;
#pragma unroll
    for (int i = 0; i < 4; ++i) {
        int idx = base + i;
        if (idx < M) s += in[idx];
    }
    sdata[t] = s;
    __syncthreads();
    for (int off = 128; off > 0; off >>= 1) {
        if (t < off) sdata[t] += sdata[t + off];
        __syncthreads();
    }
    if (t == 0) partial[b] = sdata[0];
}

__global__ void scan_partials(int* __restrict__ partial, int nb) {
    if (threadIdx.x == 0 && blockIdx.x == 0) {
        int run = 0;
        for (int i = 0; i < nb; ++i) {
            int t = partial[i];
            partial[i] = run;
            run += t;
        }
    }
}

__global__ __launch_bounds__(256) void scan_final(const int* __restrict__ in,
                                                  const int* __restrict__ partial,
                                                  int* __restrict__ outS,
                                                  int M) {
    __shared__ int sdata[256];
    int b = blockIdx.x, t = threadIdx.x;
    int base = b * 1024 + t * 4;
    int v[4];
    int s = 0;
#pragma unroll
    for (int i = 0; i < 4; ++i) {
        int idx = base + i;
        v[i] = (idx < M) ? in[idx] : 0;
        s += v[i];
    }
    sdata[t] = s;
    __syncthreads();
    for (int o = 1; o < 256; o <<= 1) {
        int tmp = 0;
        if (t >= o) tmp = sdata[t - o];
        __syncthreads();
        sdata[t] += tmp;
        __syncthreads();
    }
    int run = partial[b] + (sdata[t] - s);
#pragma unroll
    for (int i = 0; i < 4; ++i) {
        int idx = base + i;
        if (idx < M) outS[idx] = run;
        run += v[i];
    }
}

// ======================= two-pass bucket sort by dst =======================
// bucket(d) = (d*256)/N  (monotone partition of dst space)

// pass 0: per-chunk bucket histogram, written bucket-major: bh[b*nbe + blk]
__global__ __launch_bounds__(256) void bucket_hist_kernel(const int* __restrict__ dst,
                                                          int* __restrict__ bh,
                                                          long long E, int N, int nbe) {
    __shared__ int cnt[NBUCK];
    cnt[threadIdx.x] = 0;
    __syncthreads();
    long long base = (long long)blockIdx.x * SORT_CHUNK;
    long long end = base + SORT_CHUNK;
    if (end > E) end = E;
    for (long long i = base + threadIdx.x; i < end; i += 256) {
        int b = (int)(((long long)dst[i] << 8) / N);
        atomicAdd(&cnt[b], 1);
    }
    __syncthreads();
    bh[threadIdx.x * nbe + blockIdx.x] = cnt[threadIdx.x];
}

// pass 1: scatter edges into bucket-grouped tmp arrays
__global__ __launch_bounds__(256) void bucket_scatter_kernel(const int* __restrict__ src,
                                                             const int* __restrict__ dst,
                                                             const float* __restrict__ ew,
                                                             const int* __restrict__ S,
                                                             int2* __restrict__ tmp_edges,
                                                             int* __restrict__ tmp_dst,
                                                             long long E, int N, int nbe) {
    __shared__ int base_lds[NBUCK];
    __shared__ int cnt[NBUCK];
    base_lds[threadIdx.x] = S[threadIdx.x * nbe + blockIdx.x];
    cnt[threadIdx.x] = 0;
    __syncthreads();
    long long b0 = (long long)blockIdx.x * SORT_CHUNK;
    long long e1 = b0 + SORT_CHUNK;
    if (e1 > E) e1 = E;
    for (long long i = b0 + threadIdx.x; i < e1; i += 256) {
        int d = dst[i];
        int b = (int)(((long long)d << 8) / N);
        int p = base_lds[b] + atomicAdd(&cnt[b], 1);
        tmp_edges[p] = make_int2(src[i], __float_as_int(ew[i]));
        tmp_dst[p] = d;
    }
}

// pass 2: one block per bucket — LDS counting sort by exact dst.
// Emits final sorted edges + hist[] + off[] (off = segment END / inclusive prefix).
__global__ __launch_bounds__(256) void bucket_sort_kernel(const int* __restrict__ S,
                                                          const int2* __restrict__ tmp_edges,
                                                          const int* __restrict__ tmp_dst,
                                                          int2* __restrict__ edges,
                                                          int* __restrict__ hist,
                                                          int* __restrict__ off,
                                                          long long E, int N, int nbe) {
    __shared__ int cnt[512];
    __shared__ int tsum[256];
    __shared__ int pos[512];
    const int b = blockIdx.x, t = threadIdx.x;
    const int lo = (int)(((long long)b * N + 255) >> 8);
    const int hi = (int)(((long long)(b + 1) * N + 255) >> 8);  // exclusive
    const int start = S[b * nbe];
    const int end = (b == NBUCK - 1) ? (int)E : S[(b + 1) * nbe];

    cnt[t] = 0;
    cnt[t + 256] = 0;
    __syncthreads();
    for (int i = start + t; i < end; i += 256)
        atomicAdd(&cnt[tmp_dst[i] - lo], 1);
    __syncthreads();

    int a0 = cnt[2 * t], a1 = cnt[2 * t + 1];
    tsum[t] = a0 + a1;
    __syncthreads();
    for (int o = 1; o < 256; o <<= 1) {
        int v = (t >= o) ? tsum[t - o] : 0;
        __syncthreads();
        tsum[t] += v;
        __syncthreads();
    }
    int excl = tsum[t] - (a0 + a1);  // exclusive prefix of this thread's pair
    pos[2 * t]     = start + excl;
    pos[2 * t + 1] = start + excl + a0;

    int d0 = lo + 2 * t, d1 = lo + 2 * t + 1;
    if (d0 < hi) { hist[d0] = a0; off[d0] = start + excl + a0; }
    if (d1 < hi) { hist[d1] = a1; off[d1] = start + excl + a0 + a1; }
    __syncthreads();

    for (int i = start + t; i < end; i += 256) {
        int d = tmp_dst[i] - lo;
        int r = atomicAdd(&pos[d], 1);
        edges[r] = tmp_edges[i];
    }
}

// ======================= dtype conversions =======================

__global__ __launch_bounds__(256) void conv_x_kernel(const float* __restrict__ x,
                                                     __hip_bfloat16* __restrict__ xb,
                                                     long long total4) {
    long long i = (long long)blockIdx.x * 256 + threadIdx.x;
    if (i >= total4) return;
    float4 v = reinterpret_cast<const float4*>(x)[i];
    union { ushort4 u; __hip_bfloat162 h2[2]; } o;
    o.h2[0] = __float22bfloat162_rn(make_float2(v.x, v.y));
    o.h2[1] = __float22bfloat162_rn(make_float2(v.z, v.w));
    reinterpret_cast<ushort4*>(xb)[i] = o.u;
}

// Wt[j][k] = (k<128 ? Wrel[k][j] : Wroot[k-128][j]), bf16
template <int DOUT>
__global__ __launch_bounds__(256) void conv_w_kernel(const float* __restrict__ Wrel,
                                                     const float* __restrict__ Wroot,
                                                     __hip_bfloat16* __restrict__ Wt) {
    int idx = blockIdx.x * 256 + threadIdx.x;
    if (idx >= DOUT * 256) return;
    int j = idx >> 8;
    int k = idx & 255;
    float v = (k < 128) ? Wrel[(size_t)k * DOUT + j] : Wroot[(size_t)(k - 128) * DOUT + j];
    Wt[idx] = __float2bfloat16(v);
}

// =============== segmented aggregation (bf16 in/out, f32 accum) ===============
__global__ __launch_bounds__(256) void aggregate_kernel(const __hip_bfloat16* __restrict__ featb,
                                                        const int2* __restrict__ edges,
                                                        const int* __restrict__ off,
                                                        const int* __restrict__ hist,
                                                        __hip_bfloat16* __restrict__ aggb,
                                                        int N) {
    int node = blockIdx.x * 4 + (threadIdx.x >> 6);
    if (node >= N) return;
    int lane = threadIdx.x & 63;
    int cnt = hist[node];
    int end = off[node];          // inclusive prefix = segment end
    int start = end - cnt;
    float inv = 1.0f / fmaxf((float)cnt, 1.0f);

    const __hip_bfloat162* f2 = reinterpret_cast<const __hip_bfloat162*>(featb);
    float ax = 0.f, ay = 0.f;
    int e = start;
    for (; e + 7 < end; e += 8) {
        int2 ed[8];
#pragma unroll
        for (int i = 0; i < 8; ++i) ed[i] = edges[e + i];
#pragma unroll
        for (int i = 0; i < 8; ++i) {
            float w = __int_as_float(ed[i].y);
            float2 v = __bfloat1622float2(f2[(size_t)ed[i].x * 64 + lane]);
            ax += w * v.x;
            ay += w * v.y;
        }
    }
    for (; e + 3 < end; e += 4) {
        int2 ed[4];
#pragma unroll
        for (int i = 0; i < 4; ++i) ed[i] = edges[e + i];
#pragma unroll
        for (int i = 0; i < 4; ++i) {
            float w = __int_as_float(ed[i].y);
            float2 v = __bfloat1622float2(f2[(size_t)ed[i].x * 64 + lane]);
            ax += w * v.x;
            ay += w * v.y;
        }
    }
    for (; e < end; ++e) {
        int2 ed = edges[e];
        float w = __int_as_float(ed.y);
        float2 v = __bfloat1622float2(f2[(size_t)ed.x * 64 + lane]);
        ax += w * v.x;
        ay += w * v.y;
    }
    reinterpret_cast<__hip_bfloat162*>(aggb)[(size_t)node * 64 + lane] =
        __float22bfloat162_rn(make_float2(ax * inv, ay * inv));
}

// =============== MFMA GEMM: out = [Arel|Aroot] @ Wt^T + bias ===============
template <int DOUT, bool OUT_BF16>
__global__ __launch_bounds__(256) void gemm_mfma(const __hip_bfloat16* __restrict__ Arel,
                                                 const __hip_bfloat16* __restrict__ Aroot,
                                                 const __hip_bfloat16* __restrict__ Wt,
                                                 const float* __restrict__ bias,
                                                 void* __restrict__ outp,
                                                 int M) {
    const int tid = threadIdx.x;
    const int lane = tid & 63;
    const int wave = tid >> 6;
    const int lr = lane & 15;
    const int lk = lane >> 4;
    const int mbase = blockIdx.x * 64 + (wave >> 1) * 32;
    const int nbase = blockIdx.y * 64 + (wave & 1) * 32;

    bf16x8 bfrag[2][8];
#pragma unroll
    for (int ni = 0; ni < 2; ++ni) {
        const short* wrow = (const short*)Wt + (size_t)(nbase + ni * 16 + lr) * 256 + lk * 8;
#pragma unroll
        for (int kk = 0; kk < 8; ++kk)
            bfrag[ni][kk] = *reinterpret_cast<const bf16x8*>(wrow + kk * 32);
    }

    f32x4 zero = {0.f, 0.f, 0.f, 0.f};
    f32x4 acc[2][2] = {{zero, zero}, {zero, zero}};

#pragma unroll
    for (int mi = 0; mi < 2; ++mi) {
        int row = mbase + mi * 16 + lr;
        int rc = row < M ? row : M - 1;
        const short* ar = (const short*)Arel  + (size_t)rc * 128 + lk * 8;
        const short* ax = (const short*)Aroot + (size_t)rc * 128 + lk * 8;
#pragma unroll
        for (int kk = 0; kk < 4; ++kk) {
            bf16x8 af = *reinterpret_cast<const bf16x8*>(ar + kk * 32);
            acc[mi][0] = __builtin_amdgcn_mfma_f32_16x16x32_bf16(af, bfrag[0][kk], acc[mi][0], 0, 0, 0);
            acc[mi][1] = __builtin_amdgcn_mfma_f32_16x16x32_bf16(af, bfrag[1][kk], acc[mi][1], 0, 0, 0);
        }
#pragma unroll
        for (int kk = 0; kk < 4; ++kk) {
            bf16x8 af = *reinterpret_cast<const bf16x8*>(ax + kk * 32);
            acc[mi][0] = __builtin_amdgcn_mfma_f32_16x16x32_bf16(af, bfrag[0][kk + 4], acc[mi][0], 0, 0, 0);
            acc[mi][1] = __builtin_amdgcn_mfma_f32_16x16x32_bf16(af, bfrag[1][kk + 4], acc[mi][1], 0, 0, 0);
        }
    }

#pragma unroll
    for (int mi = 0; mi < 2; ++mi)
#pragma unroll
        for (int ni = 0; ni < 2; ++ni) {
            int col = nbase + ni * 16 + lr;
            float bv = bias[col];
#pragma unroll
            for (int r = 0; r < 4; ++r) {
                int row = mbase + mi * 16 + lk * 4 + r;
                if (row < M) {
                    float v = acc[mi][ni][r] + bv;
                    if (OUT_BF16)
                        ((__hip_bfloat16*)outp)[(size_t)row * DOUT + col] = __float2bfloat16(v);
                    else
                        ((float*)outp)[(size_t)row * DOUT + col] = v;
                }
            }
        }
}

// ======================= launch =======================

extern "C" void kernel_launch(void* const* d_in, const int* in_sizes, int n_in,
                              void* d_out, int out_size, void* d_ws, size_t ws_size,
                              hipStream_t stream) {
    const float* x      = (const float*)d_in[0];
    const int*   ei     = (const int*)d_in[1];
    const float* ew     = (const float*)d_in[2];
    const float* Wrel1  = (const float*)d_in[3];
    const float* b1     = (const float*)d_in[4];
    const float* Wroot1 = (const float*)d_in[5];
    const float* Wrel2  = (const float*)d_in[6];
    const float* b2     = (const float*)d_in[7];
    const float* Wroot2 = (const float*)d_in[8];
    float* out = (float*)d_out;

    const int N = in_sizes[0] / D_IN;
    const long long E = in_sizes[2];
    const int* src = ei;
    const int* dst = ei + E;

    const int nbe = (int)((E + SORT_CHUNK - 1) / SORT_CHUNK);   // chunks
    const int M = nbe * NBUCK;                                   // bucket-hist size
    const int nbM = (M + 1023) / 1024;

    // persistent workspace:
    // [hist N][off N][part 128][edges E int2]
    // [agg1b N*128 bf16][xb N*128 bf16][agg2b N*128 bf16][hb N*128 bf16][Wt1][Wt2]
    int* hist = (int*)d_ws;
    int* off  = hist + N;
    int* part = off + N;
    int2* edges = (int2*)(part + 128);
    __hip_bfloat16* agg1b = (__hip_bfloat16*)(edges + E);
    __hip_bfloat16* xb    = agg1b + (size_t)N * D_IN;
    __hip_bfloat16* agg2b = xb    + (size_t)N * D_IN;
    __hip_bfloat16* hb    = agg2b + (size_t)N * D_IN;
    __hip_bfloat16* Wt1   = hb    + (size_t)N * D_IN;
    __hip_bfloat16* Wt2   = Wt1   + 128 * 256;

    // transient (sort-time only) buffers overlapped into agg1b/agg2b:
    int* bh      = (int*)agg1b;          // M ints
    int* S       = bh + M;               // M ints (exclusive scan)
    int* tmp_dst = S + M;                // E ints
    int2* tmp_edges = (int2*)agg2b;      // E int2

    // ---- sort edges by dst (bucket pass + in-bucket counting sort) ----
    bucket_hist_kernel<<<nbe, 256, 0, stream>>>(dst, bh, E, N, nbe);
    scan_block_sums<<<nbM, 256, 0, stream>>>(bh, part, M);
    scan_partials<<<1, 64, 0, stream>>>(part, nbM);
    scan_final<<<nbM, 256, 0, stream>>>(bh, part, S, M);
    bucket_scatter_kernel<<<nbe, 256, 0, stream>>>(src, dst, ew, S, tmp_edges, tmp_dst, E, N, nbe);
    bucket_sort_kernel<<<NBUCK, 256, 0, stream>>>(S, tmp_edges, tmp_dst, edges, hist, off, E, N, nbe);

    // ---- conversions (xb does not alias sort buffers) ----
    {
        long long total4 = (long long)N * D_IN / 4;
        conv_x_kernel<<<(int)((total4 + 255) / 256), 256, 0, stream>>>(x, xb, total4);
        conv_w_kernel<128><<<(128 * 256 + 255) / 256, 256, 0, stream>>>(Wrel1, Wroot1, Wt1);
        conv_w_kernel<256><<<(256 * 256 + 255) / 256, 256, 0, stream>>>(Wrel2, Wroot2, Wt2);
    }

    const int ab = (N + 3) / 4;
    const int gx = (N + 63) / 64;

    // ---- layer 1 (aggregate overwrites the transient buffers; sort already consumed) ----
    aggregate_kernel<<<ab, 256, 0, stream>>>(xb, edges, off, hist, agg1b, N);
    {
        dim3 grid(gx, 2);
        gemm_mfma<128, true><<<grid, 256, 0, stream>>>(agg1b, xb, Wt1, b1, hb, N);
    }

    // ---- layer 2 ----
    aggregate_kernel<<<ab, 256, 0, stream>>>(hb, edges, off, hist, agg2b, N);
    {
        dim3 grid(gx, 4);
        gemm_mfma<256, false><<<grid, 256, 0, stream>>>(agg2b, hb, Wt2, b2, out, N);
    }
}

// Round 6
// 362.377 us; speedup vs baseline: 5.4066x; 1.1012x over previous
//
#include <hip/hip_runtime.h>
#include <hip/hip_bf16.h>

#define D_IN 128
#define SORT_CHUNK 4096
#define NBUCK 256

typedef __attribute__((ext_vector_type(8))) short bf16x8;
typedef __attribute__((ext_vector_type(4))) float f32x4;

// ======================= generic exclusive scan (1024/block) =======================

__global__ __launch_bounds__(256) void scan_block_sums(const int* __restrict__ in,
                                                       int* __restrict__ partial,
                                                       int M) {
    __shared__ int sdata[256];
    int b = blockIdx.x, t = threadIdx.x;
    int base = b * 1024 + t * 4;
    int s = 0;
#pragma unroll
    for (int i = 0; i < 4; ++i) {
        int idx = base + i;
        if (idx < M) s += in[idx];
    }
    sdata[t] = s;
    __syncthreads();
    for (int off = 128; off > 0; off >>= 1) {
        if (t < off) sdata[t] += sdata[t + off];
        __syncthreads();
    }
    if (t == 0) partial[b] = sdata[0];
}

__global__ void scan_partials(int* __restrict__ partial, int nb) {
    if (threadIdx.x == 0 && blockIdx.x == 0) {
        int run = 0;
        for (int i = 0; i < nb; ++i) {
            int t = partial[i];
            partial[i] = run;
            run += t;
        }
    }
}

__global__ __launch_bounds__(256) void scan_final(const int* __restrict__ in,
                                                  const int* __restrict__ partial,
                                                  int* __restrict__ outS,
                                                  int M) {
    __shared__ int sdata[256];
    int b = blockIdx.x, t = threadIdx.x;
    int base = b * 1024 + t * 4;
    int v[4];
    int s = 0;
#pragma unroll
    for (int i = 0; i < 4; ++i) {
        int idx = base + i;
        v[i] = (idx < M) ? in[idx] : 0;
        s += v[i];
    }
    sdata[t] = s;
    __syncthreads();
    for (int o = 1; o < 256; o <<= 1) {
        int tmp = 0;
        if (t >= o) tmp = sdata[t - o];
        __syncthreads();
        sdata[t] += tmp;
        __syncthreads();
    }
    int run = partial[b] + (sdata[t] - s);
#pragma unroll
    for (int i = 0; i < 4; ++i) {
        int idx = base + i;
        if (idx < M) outS[idx] = run;
        run += v[i];
    }
}

// ======================= two-pass bucket sort by dst =======================

__global__ __launch_bounds__(256) void bucket_hist_kernel(const int* __restrict__ dst,
                                                          int* __restrict__ bh,
                                                          long long E, int N, int nbe) {
    __shared__ int cnt[NBUCK];
    cnt[threadIdx.x] = 0;
    __syncthreads();
    long long base = (long long)blockIdx.x * SORT_CHUNK;
    long long end = base + SORT_CHUNK;
    if (end > E) end = E;
    for (long long i = base + threadIdx.x; i < end; i += 256) {
        int b = (int)(((long long)dst[i] << 8) / N);
        atomicAdd(&cnt[b], 1);
    }
    __syncthreads();
    bh[threadIdx.x * nbe + blockIdx.x] = cnt[threadIdx.x];
}

__global__ __launch_bounds__(256) void bucket_scatter_kernel(const int* __restrict__ src,
                                                             const int* __restrict__ dst,
                                                             const float* __restrict__ ew,
                                                             const int* __restrict__ S,
                                                             int2* __restrict__ tmp_edges,
                                                             int* __restrict__ tmp_dst,
                                                             long long E, int N, int nbe) {
    __shared__ int base_lds[NBUCK];
    __shared__ int cnt[NBUCK];
    base_lds[threadIdx.x] = S[threadIdx.x * nbe + blockIdx.x];
    cnt[threadIdx.x] = 0;
    __syncthreads();
    long long b0 = (long long)blockIdx.x * SORT_CHUNK;
    long long e1 = b0 + SORT_CHUNK;
    if (e1 > E) e1 = E;
    for (long long i = b0 + threadIdx.x; i < e1; i += 256) {
        int d = dst[i];
        int b = (int)(((long long)d << 8) / N);
        int p = base_lds[b] + atomicAdd(&cnt[b], 1);
        tmp_edges[p] = make_int2(src[i], __float_as_int(ew[i]));
        tmp_dst[p] = d;
    }
}

__global__ __launch_bounds__(256) void bucket_sort_kernel(const int* __restrict__ S,
                                                          const int2* __restrict__ tmp_edges,
                                                          const int* __restrict__ tmp_dst,
                                                          int2* __restrict__ edges,
                                                          int* __restrict__ hist,
                                                          int* __restrict__ off,
                                                          long long E, int N, int nbe) {
    __shared__ int cnt[512];
    __shared__ int tsum[256];
    __shared__ int pos[512];
    const int b = blockIdx.x, t = threadIdx.x;
    const int lo = (int)(((long long)b * N + 255) >> 8);
    const int hi = (int)(((long long)(b + 1) * N + 255) >> 8);
    const int start = S[b * nbe];
    const int end = (b == NBUCK - 1) ? (int)E : S[(b + 1) * nbe];

    cnt[t] = 0;
    cnt[t + 256] = 0;
    __syncthreads();
    for (int i = start + t; i < end; i += 256)
        atomicAdd(&cnt[tmp_dst[i] - lo], 1);
    __syncthreads();

    int a0 = cnt[2 * t], a1 = cnt[2 * t + 1];
    tsum[t] = a0 + a1;
    __syncthreads();
    for (int o = 1; o < 256; o <<= 1) {
        int v = (t >= o) ? tsum[t - o] : 0;
        __syncthreads();
        tsum[t] += v;
        __syncthreads();
    }
    int excl = tsum[t] - (a0 + a1);
    pos[2 * t]     = start + excl;
    pos[2 * t + 1] = start + excl + a0;

    int d0 = lo + 2 * t, d1 = lo + 2 * t + 1;
    if (d0 < hi) { hist[d0] = a0; off[d0] = start + excl + a0; }
    if (d1 < hi) { hist[d1] = a1; off[d1] = start + excl + a0 + a1; }
    __syncthreads();

    for (int i = start + t; i < end; i += 256) {
        int d = tmp_dst[i] - lo;
        int r = atomicAdd(&pos[d], 1);
        edges[r] = tmp_edges[i];
    }
}

// ======================= dtype conversions =======================

__global__ __launch_bounds__(256) void conv_x_kernel(const float* __restrict__ x,
                                                     __hip_bfloat16* __restrict__ xb,
                                                     long long total4) {
    long long i = (long long)blockIdx.x * 256 + threadIdx.x;
    if (i >= total4) return;
    float4 v = reinterpret_cast<const float4*>(x)[i];
    union { ushort4 u; __hip_bfloat162 h2[2]; } o;
    o.h2[0] = __float22bfloat162_rn(make_float2(v.x, v.y));
    o.h2[1] = __float22bfloat162_rn(make_float2(v.z, v.w));
    reinterpret_cast<ushort4*>(xb)[i] = o.u;
}

// Wt[j][k] = (k<128 ? Wrel[k][j] : Wroot[k-128][j]), bf16
template <int DOUT>
__global__ __launch_bounds__(256) void conv_w_kernel(const float* __restrict__ Wrel,
                                                     const float* __restrict__ Wroot,
                                                     __hip_bfloat16* __restrict__ Wt) {
    int idx = blockIdx.x * 256 + threadIdx.x;
    if (idx >= DOUT * 256) return;
    int j = idx >> 8;
    int k = idx & 255;
    float v = (k < 128) ? Wrel[(size_t)k * DOUT + j] : Wroot[(size_t)(k - 128) * DOUT + j];
    Wt[idx] = __float2bfloat16(v);
}

// =============== segmented aggregation (bf16 in/out, f32 accum) ===============
__global__ __launch_bounds__(256) void aggregate_kernel(const __hip_bfloat16* __restrict__ featb,
                                                        const int2* __restrict__ edges,
                                                        const int* __restrict__ off,
                                                        const int* __restrict__ hist,
                                                        __hip_bfloat16* __restrict__ aggb,
                                                        int N) {
    int node = blockIdx.x * 4 + (threadIdx.x >> 6);
    if (node >= N) return;
    int lane = threadIdx.x & 63;
    int cnt = hist[node];
    int end = off[node];
    int start = end - cnt;
    float inv = 1.0f / fmaxf((float)cnt, 1.0f);

    const __hip_bfloat162* f2 = reinterpret_cast<const __hip_bfloat162*>(featb);
    float ax = 0.f, ay = 0.f;
    int e = start;
    for (; e + 7 < end; e += 8) {
        int2 ed[8];
#pragma unroll
        for (int i = 0; i < 8; ++i) ed[i] = edges[e + i];
#pragma unroll
        for (int i = 0; i < 8; ++i) {
            float w = __int_as_float(ed[i].y);
            float2 v = __bfloat1622float2(f2[(size_t)ed[i].x * 64 + lane]);
            ax += w * v.x;
            ay += w * v.y;
        }
    }
    for (; e + 3 < end; e += 4) {
        int2 ed[4];
#pragma unroll
        for (int i = 0; i < 4; ++i) ed[i] = edges[e + i];
#pragma unroll
        for (int i = 0; i < 4; ++i) {
            float w = __int_as_float(ed[i].y);
            float2 v = __bfloat1622float2(f2[(size_t)ed[i].x * 64 + lane]);
            ax += w * v.x;
            ay += w * v.y;
        }
    }
    for (; e < end; ++e) {
        int2 ed = edges[e];
        float w = __int_as_float(ed.y);
        float2 v = __bfloat1622float2(f2[(size_t)ed.x * 64 + lane]);
        ax += w * v.x;
        ay += w * v.y;
    }
    reinterpret_cast<__hip_bfloat162*>(aggb)[(size_t)node * 64 + lane] =
        __float22bfloat162_rn(make_float2(ax * inv, ay * inv));
}

// =============== MFMA GEMM v2: 128x128 block tile, 64x64 wave tile ===============
// out = [Arel|Aroot] @ Wt^T + bias.  Wt: [DOUT][256] bf16.
// 1D grid, y(col-strip)-fastest + bijective XCD swizzle so col-strips sharing
// an A-panel land contiguously on one XCD (L2 reuse of A).
template <int DOUT, bool OUT_BF16>
__global__ __launch_bounds__(256) void gemm_mfma2(const __hip_bfloat16* __restrict__ Arel,
                                                  const __hip_bfloat16* __restrict__ Aroot,
                                                  const __hip_bfloat16* __restrict__ Wt,
                                                  const float* __restrict__ bias,
                                                  void* __restrict__ outp,
                                                  int M) {
    constexpr int NY = DOUT / 128;
    // bijective XCD swizzle (m204): dispatch-index -> tile-index such that each
    // XCD processes a contiguous tile range.
    const int nb = gridDim.x;
    const int orig = blockIdx.x;
    const int xcd = orig & 7;
    const int lid = orig >> 3;
    const int q = nb >> 3, r = nb & 7;
    const int wgid = (xcd < r ? xcd * (q + 1) : r * (q + 1) + (xcd - r) * q) + lid;

    const int ty = wgid % NY;          // col strip (fastest)
    const int tx = wgid / NY;          // row panel
    const int tid = threadIdx.x;
    const int lane = tid & 63;
    const int wave = tid >> 6;
    const int lr = lane & 15;
    const int lk = lane >> 4;
    const int mbase = tx * 128 + (wave >> 1) * 64;
    const int nbase = ty * 128 + (wave & 1) * 64;

    // row addresses (clamped) for 4 mi tiles
    const short* arow[4];
    const short* xrow[4];
#pragma unroll
    for (int mi = 0; mi < 4; ++mi) {
        int row = mbase + mi * 16 + lr;
        int rc = row < M ? row : M - 1;
        arow[mi] = (const short*)Arel  + (size_t)rc * 128 + lk * 8;
        xrow[mi] = (const short*)Aroot + (size_t)rc * 128 + lk * 8;
    }
    const short* wrow[4];
#pragma unroll
    for (int ni = 0; ni < 4; ++ni)
        wrow[ni] = (const short*)Wt + (size_t)(nbase + ni * 16 + lr) * 256 + lk * 8;

    f32x4 zero = {0.f, 0.f, 0.f, 0.f};
    f32x4 acc[4][4];
#pragma unroll
    for (int mi = 0; mi < 4; ++mi)
#pragma unroll
        for (int ni = 0; ni < 4; ++ni) acc[mi][ni] = zero;

#pragma unroll
    for (int kk = 0; kk < 8; ++kk) {
        bf16x8 a[4], b[4];
#pragma unroll
        for (int mi = 0; mi < 4; ++mi)
            a[mi] = (kk < 4)
                ? *reinterpret_cast<const bf16x8*>(arow[mi] + kk * 32)
                : *reinterpret_cast<const bf16x8*>(xrow[mi] + (kk - 4) * 32);
#pragma unroll
        for (int ni = 0; ni < 4; ++ni)
            b[ni] = *reinterpret_cast<const bf16x8*>(wrow[ni] + kk * 32);
#pragma unroll
        for (int mi = 0; mi < 4; ++mi)
#pragma unroll
            for (int ni = 0; ni < 4; ++ni)
                acc[mi][ni] = __builtin_amdgcn_mfma_f32_16x16x32_bf16(a[mi], b[ni], acc[mi][ni], 0, 0, 0);
    }

#pragma unroll
    for (int mi = 0; mi < 4; ++mi)
#pragma unroll
        for (int ni = 0; ni < 4; ++ni) {
            int col = nbase + ni * 16 + lr;
            float bv = bias[col];
#pragma unroll
            for (int rr = 0; rr < 4; ++rr) {
                int row = mbase + mi * 16 + lk * 4 + rr;
                if (row < M) {
                    float v = acc[mi][ni][rr] + bv;
                    if (OUT_BF16)
                        ((__hip_bfloat16*)outp)[(size_t)row * DOUT + col] = __float2bfloat16(v);
                    else
                        ((float*)outp)[(size_t)row * DOUT + col] = v;
                }
            }
        }
}

// ======================= launch =======================

extern "C" void kernel_launch(void* const* d_in, const int* in_sizes, int n_in,
                              void* d_out, int out_size, void* d_ws, size_t ws_size,
                              hipStream_t stream) {
    const float* x      = (const float*)d_in[0];
    const int*   ei     = (const int*)d_in[1];
    const float* ew     = (const float*)d_in[2];
    const float* Wrel1  = (const float*)d_in[3];
    const float* b1     = (const float*)d_in[4];
    const float* Wroot1 = (const float*)d_in[5];
    const float* Wrel2  = (const float*)d_in[6];
    const float* b2     = (const float*)d_in[7];
    const float* Wroot2 = (const float*)d_in[8];
    float* out = (float*)d_out;

    const int N = in_sizes[0] / D_IN;
    const long long E = in_sizes[2];
    const int* src = ei;
    const int* dst = ei + E;

    const int nbe = (int)((E + SORT_CHUNK - 1) / SORT_CHUNK);
    const int M = nbe * NBUCK;
    const int nbM = (M + 1023) / 1024;

    int* hist = (int*)d_ws;
    int* off  = hist + N;
    int* part = off + N;
    int2* edges = (int2*)(part + 128);
    __hip_bfloat16* agg1b = (__hip_bfloat16*)(edges + E);
    __hip_bfloat16* xb    = agg1b + (size_t)N * D_IN;
    __hip_bfloat16* agg2b = xb    + (size_t)N * D_IN;
    __hip_bfloat16* hb    = agg2b + (size_t)N * D_IN;
    __hip_bfloat16* Wt1   = hb    + (size_t)N * D_IN;
    __hip_bfloat16* Wt2   = Wt1   + 128 * 256;

    // transient (sort-time only) buffers overlapped into agg1b/agg2b:
    int* bh      = (int*)agg1b;
    int* S       = bh + M;
    int* tmp_dst = S + M;
    int2* tmp_edges = (int2*)agg2b;

    // ---- sort edges by dst ----
    bucket_hist_kernel<<<nbe, 256, 0, stream>>>(dst, bh, E, N, nbe);
    scan_block_sums<<<nbM, 256, 0, stream>>>(bh, part, M);
    scan_partials<<<1, 64, 0, stream>>>(part, nbM);
    scan_final<<<nbM, 256, 0, stream>>>(bh, part, S, M);
    bucket_scatter_kernel<<<nbe, 256, 0, stream>>>(src, dst, ew, S, tmp_edges, tmp_dst, E, N, nbe);
    bucket_sort_kernel<<<NBUCK, 256, 0, stream>>>(S, tmp_edges, tmp_dst, edges, hist, off, E, N, nbe);

    // ---- conversions ----
    {
        long long total4 = (long long)N * D_IN / 4;
        conv_x_kernel<<<(int)((total4 + 255) / 256), 256, 0, stream>>>(x, xb, total4);
        conv_w_kernel<128><<<(128 * 256 + 255) / 256, 256, 0, stream>>>(Wrel1, Wroot1, Wt1);
        conv_w_kernel<256><<<(256 * 256 + 255) / 256, 256, 0, stream>>>(Wrel2, Wroot2, Wt2);
    }

    const int ab = (N + 3) / 4;
    const int gx = (N + 127) / 128;   // 128-row panels

    // ---- layer 1 ----
    aggregate_kernel<<<ab, 256, 0, stream>>>(xb, edges, off, hist, agg1b, N);
    gemm_mfma2<128, true><<<gx * 1, 256, 0, stream>>>(agg1b, xb, Wt1, b1, hb, N);

    // ---- layer 2 ----
    aggregate_kernel<<<ab, 256, 0, stream>>>(hb, edges, off, hist, agg2b, N);
    gemm_mfma2<256, false><<<gx * 2, 256, 0, stream>>>(agg2b, hb, Wt2, b2, out, N);
}